// Round 11
// baseline (848.029 us; speedup 1.0000x reference)
//
#include <hip/hip_runtime.h>
#include <hip/hip_bf16.h>

#define THREADS 256
#define NB_MAX 400   // buckets = ceil(N/256); N=100000 -> 391
#define NPH 13       // src phases (src>>13 -> 8192-node slices = 2 MB of xq)
#define NB_AGG 1024  // persistent agg1 grid (one generation)
#define OWN 13       // nodes owned per half-wave: OWN * NB_AGG*8 >= Npad

typedef __attribute__((ext_vector_type(8))) short bf16x8;
typedef __attribute__((ext_vector_type(4))) float f32x4;
typedef __attribute__((ext_vector_type(2))) float f32x2;

__device__ __forceinline__ unsigned short f2b(float f) {
    __hip_bfloat16 h = __float2bfloat16(f);
    return *reinterpret_cast<unsigned short*>(&h);
}
__device__ __forceinline__ unsigned char f2q(float v) {
    int q = __builtin_amdgcn_cvt_pk_fp8_f32(v, v, 0, false);
    return (unsigned char)(q & 0xff);
}
__device__ __forceinline__ void gload_lds16(const void* g, void* l) {
    __builtin_amdgcn_global_load_lds(
        (const __attribute__((address_space(1))) void*)g,
        (__attribute__((address_space(3))) void*)l, 16, 0, 0);
}

// ---------------- merged: bucket histogram (blocks < nsb) + converts (rest) ----------------
__global__ __launch_bounds__(256) void k_hist_cvt(
    const int* __restrict__ dst, int E, int nbk, int* __restrict__ gcnt, int nsb,
    const float* __restrict__ x, unsigned short* __restrict__ xb, unsigned char* __restrict__ xq,
    int N, int Npad,
    const float* __restrict__ W1l, const float* __restrict__ W1r,
    const float* __restrict__ W2l, const float* __restrict__ W2r,
    unsigned short* __restrict__ WbT, unsigned short* __restrict__ WbT2) {
    __shared__ int lc[NB_MAX];
    const int tid = threadIdx.x;
    if ((int)blockIdx.x < nsb) {
        for (int i = tid; i < nbk; i += 256) lc[i] = 0;
        __syncthreads();
        const int stride = nsb * 256;
        for (int e = blockIdx.x * 256 + tid; e < E; e += stride)
            atomicAdd(&lc[dst[e] >> 8], 1);
        __syncthreads();
        for (int i = tid; i < nbk; i += 256)
            if (lc[i]) atomicAdd(&gcnt[i], lc[i]);
        return;
    }
    int i = ((int)blockIdx.x - nsb) * 256 + tid;
    const int nxu = Npad * 32;                 // x units (8 elems each)
    if (i < nxu) {
        int row = i >> 5;
        unsigned short o[8];
        int q0 = 0, q1 = 0;
        if (row < N) {
            float4 v0 = reinterpret_cast<const float4*>(x)[2 * (size_t)i];
            float4 v1 = reinterpret_cast<const float4*>(x)[2 * (size_t)i + 1];
            o[0] = f2b(v0.x); o[1] = f2b(v0.y); o[2] = f2b(v0.z); o[3] = f2b(v0.w);
            o[4] = f2b(v1.x); o[5] = f2b(v1.y); o[6] = f2b(v1.z); o[7] = f2b(v1.w);
            q0 = __builtin_amdgcn_cvt_pk_fp8_f32(v0.x, v0.y, q0, false);
            q0 = __builtin_amdgcn_cvt_pk_fp8_f32(v0.z, v0.w, q0, true);
            q1 = __builtin_amdgcn_cvt_pk_fp8_f32(v1.x, v1.y, q1, false);
            q1 = __builtin_amdgcn_cvt_pk_fp8_f32(v1.z, v1.w, q1, true);
        } else {
            #pragma unroll
            for (int j = 0; j < 8; ++j) o[j] = 0;
        }
        reinterpret_cast<uint4*>(xb)[i] = *reinterpret_cast<uint4*>(o);
        reinterpret_cast<uint2*>(xq)[i] = make_uint2((unsigned)q0, (unsigned)q1);
        return;
    }
    int idx = i - nxu;
    if (idx < 131072) {
        int n = idx >> 9, k = idx & 511;
        float v = (k < 256) ? W1l[(size_t)k * 256 + n] : W1r[(size_t)(k - 256) * 256 + n];
        WbT[idx] = f2b(v);
    } else if (idx < 131072 + 20480) {
        int j = idx - 131072;
        int n = j >> 8, k = j & 255;
        float v = (n < 40) ? W2l[(size_t)k * 40 + n] : W2r[(size_t)k * 40 + (n - 40)];
        WbT2[j] = f2b(v);
    }
}

// ---------------- scan buckets ----------------
__global__ __launch_bounds__(512) void k_scanb(const int* __restrict__ gcnt, int* __restrict__ bptr,
                                               int* __restrict__ gcur, int nbk, int E) {
    __shared__ int sm[512];
    const int t = threadIdx.x;
    int v = (t < nbk) ? gcnt[t] : 0;
    sm[t] = v; __syncthreads();
    for (int off = 1; off < 512; off <<= 1) {
        int u = (t >= off) ? sm[t - off] : 0; __syncthreads();
        sm[t] += u; __syncthreads();
    }
    if (t < nbk) {
        int ex = sm[t] - v;
        bptr[t] = ex;
        gcur[t] = ex;
    }
    if (t == 0) bptr[nbk] = E;
}

// ---------------- scatter edges into bucket regions (packed: src<<8 | dst&255) ----------------
__global__ __launch_bounds__(256) void k_bucket_scatter(const int* __restrict__ src, const int* __restrict__ dst,
                                                        int* __restrict__ gcur, unsigned* __restrict__ pairs,
                                                        int E, int nbk) {
    __shared__ int cnt[NB_MAX];
    __shared__ int base[NB_MAX];
    const int tid = threadIdx.x;
    const int e0 = blockIdx.x * 8192;
    for (int i = tid; i < nbk; i += 256) cnt[i] = 0;
    __syncthreads();
    #pragma unroll
    for (int j = 0; j < 32; ++j) {
        int e = e0 + j * 256 + tid;
        if (e < E) atomicAdd(&cnt[dst[e] >> 8], 1);
    }
    __syncthreads();
    for (int i = tid; i < nbk; i += 256)
        base[i] = cnt[i] ? atomicAdd(&gcur[i], cnt[i]) : 0;
    __syncthreads();
    #pragma unroll
    for (int j = 0; j < 32; ++j) {
        int e = e0 + j * 256 + tid;
        if (e < E) {
            int d = dst[e];
            int p = atomicAdd(&base[d >> 8], 1);
            pairs[p] = ((unsigned)src[e] << 8) | ((unsigned)d & 255u);
        }
    }
}

// ---------------- per-bucket CSR build with per-node src-phase counting sort + rowptr2 export ----------------
__global__ __launch_bounds__(256) void k_bucket_csr(const int* __restrict__ bptr, const unsigned* __restrict__ pairs,
                                                    int* __restrict__ rowptr, int* __restrict__ rowptr2,
                                                    float* __restrict__ dinv,
                                                    int* __restrict__ csr_src, int N, int nbk, int E) {
    __shared__ int pc[256 * NPH];   // per-(node, phase) counts -> offsets -> cursors
    __shared__ int deg[256];
    __shared__ int sm[256];
    __shared__ int nodebase[256];
    const int b = blockIdx.x;
    const int tid = threadIdx.x;
    const int e0 = bptr[b], e1 = bptr[b + 1];

    #pragma unroll
    for (int i = 0; i < NPH; ++i) pc[i * 256 + tid] = 0;   // pc laid out [ph][node]
    __syncthreads();
    // pass A: count per (node, phase)
    for (int e = e0 + tid; e < e1; e += 256) {
        unsigned u = pairs[e];
        int n = (int)(u & 255u);
        int ph = (int)(u >> 8) >> 13;
        atomicAdd(&pc[ph * 256 + n], 1);
    }
    __syncthreads();
    // per-node: degree + exclusive scan over phases
    int run = 0;
    #pragma unroll
    for (int ph = 0; ph < NPH; ++ph) {
        int c = pc[ph * 256 + tid];
        pc[ph * 256 + tid] = run;
        run += c;
    }
    int d = run;
    deg[tid] = d;
    sm[tid] = d; __syncthreads();
    for (int off = 1; off < 256; off <<= 1) {
        int u = (tid >= off) ? sm[tid - off] : 0; __syncthreads();
        sm[tid] += u; __syncthreads();
    }
    int ex = sm[tid] - d;
    int node = (b << 8) + tid;
    int nb_ = e0 + ex;
    nodebase[tid] = nb_;
    if (node < N) {
        rowptr[node] = nb_;
        dinv[node] = 1.0f / (float)max(d, 1);
    }
    if (b == nbk - 1 && tid == 0) rowptr[N] = E;
    __syncthreads();
    // convert per-node phase offsets to global cursors + export segment starts
    #pragma unroll
    for (int ph = 0; ph < NPH; ++ph) {
        int cu = pc[ph * 256 + tid] + nodebase[tid];
        pc[ph * 256 + tid] = cu;
        if (node < N) rowptr2[(size_t)ph * N + node] = cu;
    }
    if (node < N) rowptr2[(size_t)NPH * N + node] = nb_ + d;
    __syncthreads();
    // pass B: place edges at cursor(node, phase)
    for (int e = e0 + tid; e < e1; e += 256) {
        unsigned u = pairs[e];
        int n = (int)(u & 255u);
        int s = (int)(u >> 8);
        int p = atomicAdd(&pc[(s >> 13) * 256 + n], 1);
        csr_src[p] = s;
    }
}

// ---------------- layer-1 gather (fp8): persistent grid, phase-outer, OWN nodes per half-wave ----------------
__global__ __launch_bounds__(256) void k_agg1(const int* __restrict__ rowptr2, const int* __restrict__ csr_src,
                                              const float* __restrict__ dinv, const unsigned char* __restrict__ xq,
                                              unsigned short* __restrict__ aggb, int N, int Npad, int H) {
    const int tid = threadIdx.x;
    const int hw = blockIdx.x * 8 + (tid >> 5);   // global half-wave id
    const int lane = tid & 31;
    const unsigned char* xl = xq + (size_t)lane * 8;

    f32x2 acc[OWN][4];
    #pragma unroll
    for (int i = 0; i < OWN; ++i)
        #pragma unroll
        for (int j = 0; j < 4; ++j) acc[i][j] = (f32x2){0.f, 0.f};

    for (int ph = 0; ph < NPH; ++ph) {
        #pragma unroll
        for (int i = 0; i < OWN; ++i) {
            const int node = hw + i * H;
            if (node >= N) continue;
            const int s0 = rowptr2[(size_t)ph * N + node];
            const int s1 = rowptr2[(size_t)(ph + 1) * N + node];
            for (int eb = s0; eb < s1; eb += 32) {
                int cnt = min(32, s1 - eb);
                int sidx = (eb + lane < s1) ? csr_src[eb + lane] : 0;
                for (int j = 0; j < cnt; ++j) {
                    int s = __shfl(sidx, j, 32);
                    uint2 v = *reinterpret_cast<const uint2*>(xl + (size_t)s * 256);
                    acc[i][0] += __builtin_amdgcn_cvt_pk_f32_fp8((int)v.x, false);
                    acc[i][1] += __builtin_amdgcn_cvt_pk_f32_fp8((int)v.x, true);
                    acc[i][2] += __builtin_amdgcn_cvt_pk_f32_fp8((int)v.y, false);
                    acc[i][3] += __builtin_amdgcn_cvt_pk_f32_fp8((int)v.y, true);
                }
            }
        }
        __syncthreads();   // pace the block's half-waves through phases together
    }

    #pragma unroll
    for (int i = 0; i < OWN; ++i) {
        const int node = hw + i * H;
        if (node < N) {
            const float ds = dinv[node];
            unsigned short o[8];
            #pragma unroll
            for (int j = 0; j < 4; ++j) {
                o[2 * j + 0] = f2b(acc[i][j].x * ds);
                o[2 * j + 1] = f2b(acc[i][j].y * ds);
            }
            *reinterpret_cast<uint4*>(aggb + (size_t)node * 256 + lane * 8) = *reinterpret_cast<uint4*>(o);
        } else if (node < Npad) {
            *reinterpret_cast<uint4*>(aggb + (size_t)node * 256 + lane * 8) = make_uint4(0, 0, 0, 0);
        }
    }
}

// ---------------- GEMM1 (bf16 MFMA, 512 thr, 128x256 tile): h = relu([agg|x] @ [W1l;W1r] + b1) ----------------
__global__ __launch_bounds__(512) void k_gemm1(
    const unsigned short* __restrict__ aggb, const unsigned short* __restrict__ xb,
    const unsigned short* __restrict__ WbT, const float* __restrict__ b1,
    unsigned short* __restrict__ hb, int M)
{
    __shared__ unsigned short As[128 * 64];   // 128 rows (M) x 64 k
    __shared__ unsigned short Bs[256 * 64];   // 256 rows (N) x 64 k

    const int tid  = threadIdx.x;
    const int lane = tid & 63;
    const int wave = tid >> 6;                // 0..7
    const int row0 = blockIdx.x * 128;
    const int wm0  = (wave >> 2) * 64;        // 0 or 64
    const int wn0  = (wave & 3) * 64;         // 0,64,128,192

    const int ldr = lane >> 3;                       // row within 8-row chunk
    const int lsw = ((lane & 7) ^ ldr) * 8;          // swizzled global 8-elem slot

    f32x4 acc[4][4];
    #pragma unroll
    for (int m = 0; m < 4; ++m)
        #pragma unroll
        for (int n = 0; n < 4; ++n)
            acc[m][n] = (f32x4){0.f, 0.f, 0.f, 0.f};

    for (int kt = 0; kt < 8; ++kt) {
        const unsigned short* Abase = (kt < 4) ? aggb : xb;
        const int kcol = (kt & 3) * 64;
        __syncthreads();
        #pragma unroll
        for (int i = 0; i < 2; ++i) {
            const int c = wave * 2 + i;              // A chunk 0..15
            const unsigned short* ga = Abase + (size_t)(row0 + c * 8 + ldr) * 256 + kcol + lsw;
            gload_lds16(ga, &As[c * 512]);
        }
        #pragma unroll
        for (int i = 0; i < 4; ++i) {
            const int c = wave * 4 + i;              // B chunk 0..31
            const unsigned short* gb = WbT + (size_t)(c * 8 + ldr) * 512 + kt * 64 + lsw;
            gload_lds16(gb, &Bs[c * 512]);
        }
        __syncthreads();
        #pragma unroll
        for (int kk = 0; kk < 2; ++kk) {
            bf16x8 af[4], bf[4];
            #pragma unroll
            for (int m = 0; m < 4; ++m) {
                const int r = wm0 + m * 16 + (lane & 15);
                const int s = (kk * 4 + (lane >> 4)) ^ (r & 7);
                af[m] = *reinterpret_cast<const bf16x8*>(&As[r * 64 + s * 8]);
            }
            #pragma unroll
            for (int n = 0; n < 4; ++n) {
                const int r = wn0 + n * 16 + (lane & 15);
                const int s = (kk * 4 + (lane >> 4)) ^ (r & 7);
                bf[n] = *reinterpret_cast<const bf16x8*>(&Bs[r * 64 + s * 8]);
            }
            #pragma unroll
            for (int m = 0; m < 4; ++m)
                #pragma unroll
                for (int n = 0; n < 4; ++n)
                    acc[m][n] = __builtin_amdgcn_mfma_f32_16x16x32_bf16(af[m], bf[n], acc[m][n], 0, 0, 0);
        }
    }

    const int crow = (lane >> 4) * 4;
    const int ccol = lane & 15;
    #pragma unroll
    for (int n = 0; n < 4; ++n) {
        const int col = wn0 + n * 16 + ccol;
        const float bias = b1[col];
        #pragma unroll
        for (int m = 0; m < 4; ++m) {
            const int rbase = row0 + wm0 + m * 16 + crow;
            #pragma unroll
            for (int r = 0; r < 4; ++r) {
                const int row = rbase + r;
                if (row < M) {
                    float v = fmaxf(acc[m][n][r] + bias, 0.f);
                    hb[(size_t)row * 256 + col] = f2b(v);
                }
            }
        }
    }
}

// ---------------- GEMM2 (bf16 MFMA): [Tq|Up] = h @ [W2l|W2r]; t in fp8, Up includes +b2 ----------------
__global__ __launch_bounds__(256) void k_gemm2(
    const unsigned short* __restrict__ hb, const unsigned short* __restrict__ WbT2,
    const float* __restrict__ b2,
    unsigned char* __restrict__ Tq, float* __restrict__ Up, int M)
{
    __shared__ unsigned short As[128 * 64];
    __shared__ unsigned short Bs2[80 * 264];   // padded stride 264 -> conflict-free frag reads

    const int tid  = threadIdx.x;
    const int lane = tid & 63;
    const int wave = tid >> 6;
    const int row0 = blockIdx.x * 128;

    const int ldr = lane >> 3;
    const int lsw = ((lane & 7) ^ ldr) * 8;

    // load B [80][256] into padded LDS once
    for (int idx = tid; idx < 80 * 32; idx += 256) {
        int row = idx >> 5, un = idx & 31;
        uint4 d = *reinterpret_cast<const uint4*>(WbT2 + (size_t)row * 256 + un * 8);
        *reinterpret_cast<uint4*>(&Bs2[row * 264 + un * 8]) = d;
    }

    f32x4 acc[2][5];
    #pragma unroll
    for (int m = 0; m < 2; ++m)
        #pragma unroll
        for (int n = 0; n < 5; ++n)
            acc[m][n] = (f32x4){0.f, 0.f, 0.f, 0.f};

    for (int kt = 0; kt < 4; ++kt) {
        __syncthreads();
        #pragma unroll
        for (int i = 0; i < 4; ++i) {
            const int c = wave * 4 + i;
            const unsigned short* ga = hb + (size_t)(row0 + c * 8 + ldr) * 256 + kt * 64 + lsw;
            gload_lds16(ga, &As[c * 512]);
        }
        __syncthreads();
        #pragma unroll
        for (int kk = 0; kk < 2; ++kk) {
            bf16x8 af[2], bf[5];
            #pragma unroll
            for (int m = 0; m < 2; ++m) {
                const int r = wave * 32 + m * 16 + (lane & 15);
                const int s = (kk * 4 + (lane >> 4)) ^ (r & 7);
                af[m] = *reinterpret_cast<const bf16x8*>(&As[(r & 127) * 64 + s * 8]);
            }
            #pragma unroll
            for (int n = 0; n < 5; ++n) {
                const int r = n * 16 + (lane & 15);
                bf[n] = *reinterpret_cast<const bf16x8*>(&Bs2[r * 264 + kt * 64 + kk * 32 + (lane >> 4) * 8]);
            }
            #pragma unroll
            for (int m = 0; m < 2; ++m)
                #pragma unroll
                for (int n = 0; n < 5; ++n)
                    acc[m][n] = __builtin_amdgcn_mfma_f32_16x16x32_bf16(af[m], bf[n], acc[m][n], 0, 0, 0);
        }
    }

    const int crow = (lane >> 4) * 4;
    const int ccol = lane & 15;
    #pragma unroll
    for (int n = 0; n < 5; ++n) {
        const int col = n * 16 + ccol;        // 0..79
        #pragma unroll
        for (int m = 0; m < 2; ++m) {
            const int rbase = row0 + wave * 32 + m * 16 + crow;
            #pragma unroll
            for (int r = 0; r < 4; ++r) {
                const int row = rbase + r;
                if (row < M) {
                    float v = acc[m][n][r];
                    if (col < 40)
                        Tq[(size_t)row * 40 + col] = f2q(v);
                    else
                        Up[(size_t)row * 40 + (col - 40)] = v + b2[col - 40];
                }
            }
        }
    }
}

// ---------------- fused layer-2 gather (fp8 Tq) + log_softmax: wave per node, 6 edges per VMEM ----------------
__global__ __launch_bounds__(256) void k_final(const int* __restrict__ rowptr, const int* __restrict__ csr_src,
                                               const float* __restrict__ dinv, const unsigned char* __restrict__ Tq,
                                               const float* __restrict__ Up, float* __restrict__ out, int N) {
    int gid = blockIdx.x * THREADS + threadIdx.x;
    int node = gid >> 6, lane = gid & 63;
    if (node >= N) return;
    const int e0 = rowptr[node], e1 = rowptr[node + 1];
    const int g = lane / 10;
    const int c = lane % 10;
    float a0 = 0.f, a1 = 0.f, a2 = 0.f, a3 = 0.f;
    for (int eb = e0; eb < e1; eb += 64) {
        int sidx = (eb + lane < e1) ? csr_src[eb + lane] : 0;
        int nn = min(64, e1 - eb);
        for (int jb = 0; jb < nn; jb += 6) {
            int ei = jb + g;
            bool valid = (g < 6) && (ei < nn);
            int s = __shfl(sidx, ei & 63, 64);
            if (valid) {
                unsigned u = *reinterpret_cast<const unsigned*>(Tq + (size_t)s * 40 + c * 4);
                f32x2 lo = __builtin_amdgcn_cvt_pk_f32_fp8((int)u, false);
                f32x2 hi = __builtin_amdgcn_cvt_pk_f32_fp8((int)u, true);
                a0 += lo.x; a1 += lo.y;
                a2 += hi.x; a3 += hi.y;
            }
        }
    }
    float t0 = a0, t1 = a1, t2 = a2, t3 = a3;
    #pragma unroll
    for (int gg = 1; gg < 6; ++gg) {
        t0 += __shfl(a0, c + 10 * gg, 64);
        t1 += __shfl(a1, c + 10 * gg, 64);
        t2 += __shfl(a2, c + 10 * gg, 64);
        t3 += __shfl(a3, c + 10 * gg, 64);
    }
    float v0 = -1e30f, v1 = -1e30f, v2 = -1e30f, v3 = -1e30f;
    if (lane < 10) {
        const float ds = dinv[node];
        float4 up = *reinterpret_cast<const float4*>(Up + (size_t)node * 40 + lane * 4);
        v0 = t0 * ds + up.x; v1 = t1 * ds + up.y;
        v2 = t2 * ds + up.z; v3 = t3 * ds + up.w;
    }
    float m = fmaxf(fmaxf(v0, v1), fmaxf(v2, v3));
    #pragma unroll
    for (int o = 8; o > 0; o >>= 1) m = fmaxf(m, __shfl_xor(m, o, 16));
    float e = 0.f;
    if (lane < 10) e = expf(v0 - m) + expf(v1 - m) + expf(v2 - m) + expf(v3 - m);
    float ssum = e;
    #pragma unroll
    for (int o = 8; o > 0; o >>= 1) ssum += __shfl_xor(ssum, o, 16);
    float ls = logf(ssum);
    if (lane < 10) {
        float4 o4;
        o4.x = v0 - m - ls; o4.y = v1 - m - ls;
        o4.z = v2 - m - ls; o4.w = v3 - m - ls;
        *reinterpret_cast<float4*>(out + (size_t)node * 40 + lane * 4) = o4;
    }
}

extern "C" void kernel_launch(void* const* d_in, const int* in_sizes, int n_in,
                              void* d_out, int out_size, void* d_ws, size_t ws_size,
                              hipStream_t stream) {
    const float* x   = (const float*)d_in[0];
    const int*   ei  = (const int*)d_in[1];
    const float* W1l = (const float*)d_in[2];
    const float* W1r = (const float*)d_in[3];
    const float* b1  = (const float*)d_in[4];
    const float* W2l = (const float*)d_in[5];
    const float* W2r = (const float*)d_in[6];
    const float* b2  = (const float*)d_in[7];
    float* out = (float*)d_out;

    const int N = in_sizes[0] / 256;
    const int E = in_sizes[1] / 2;
    const int Npad = ((N + 127) / 128) * 128;
    const int nbk = (N + 255) / 256;
    const int* src = ei;
    const int* dst = ei + E;

    char* ws = (char*)d_ws;
    size_t off = 0;
    int*   gcnt    = (int*)(ws + off); off += (size_t)NB_MAX * 4;
    int*   bptr    = (int*)(ws + off); off += (size_t)(NB_MAX + 1) * 4;
    int*   gcur    = (int*)(ws + off); off += (size_t)NB_MAX * 4;
    int*   rowptr  = (int*)(ws + off); off += (size_t)(N + 1) * 4;
    float* dinv    = (float*)(ws + off); off += (size_t)N * 4;
    off = (off + 255) & ~(size_t)255;
    int*   rowptr2 = (int*)(ws + off); off += (size_t)(NPH + 1) * N * 4;
    off = (off + 255) & ~(size_t)255;
    unsigned* pairs = (unsigned*)(ws + off); off += (size_t)E * 4;
    int*   csr_src = (int*)(ws + off); off += (size_t)E * 4;
    off = (off + 255) & ~(size_t)255;
    unsigned short* xb   = (unsigned short*)(ws + off); off += (size_t)Npad * 256 * 2;
    unsigned char*  xq   = (unsigned char*)(ws + off);  off += (size_t)Npad * 256;
    unsigned short* aggb = (unsigned short*)(ws + off); off += (size_t)Npad * 256 * 2;
    unsigned short* hb   = (unsigned short*)(ws + off); off += (size_t)Npad * 256 * 2;
    unsigned short* WbT  = (unsigned short*)(ws + off); off += (size_t)256 * 512 * 2;
    unsigned short* WbT2 = (unsigned short*)(ws + off); off += (size_t)80 * 256 * 2;
    off = (off + 255) & ~(size_t)255;
    unsigned char*  Tq   = (unsigned char*)(ws + off);  off += (size_t)Npad * 40;
    off = (off + 255) & ~(size_t)255;
    float*          Up   = (float*)(ws + off);          off += (size_t)Npad * 40 * 4;

    hipMemsetAsync(gcnt, 0, (size_t)NB_MAX * 4, stream);

    const int nsb = (E + 8191) / 8192;
    const int ncvt_blocks = (Npad * 32 + 131072 + 20480 + THREADS - 1) / THREADS;
    k_hist_cvt<<<nsb + ncvt_blocks, THREADS, 0, stream>>>(dst, E, nbk, gcnt, nsb,
                                                          x, xb, xq, N, Npad,
                                                          W1l, W1r, W2l, W2r, WbT, WbT2);
    k_scanb<<<1, 512, 0, stream>>>(gcnt, bptr, gcur, nbk, E);
    k_bucket_scatter<<<nsb, THREADS, 0, stream>>>(src, dst, gcur, pairs, E, nbk);
    k_bucket_csr<<<nbk, THREADS, 0, stream>>>(bptr, pairs, rowptr, rowptr2, dinv, csr_src, N, nbk, E);

    const int H = NB_AGG * 8;   // half-waves in the persistent grid; OWN*H >= Npad
    k_agg1<<<NB_AGG, THREADS, 0, stream>>>(rowptr2, csr_src, dinv, xq, aggb, N, Npad, H);

    k_gemm1<<<Npad / 128, 512, 0, stream>>>(aggb, xb, WbT, b1, hb, N);

    k_gemm2<<<Npad / 128, THREADS, 0, stream>>>(hb, WbT2, b2, Tq, Up, N);

    k_final<<<((size_t)N * 64 + THREADS - 1) / THREADS, THREADS, 0, stream>>>(rowptr, csr_src, dinv, Tq, Up, out, N);
}

// Round 12
// 399.784 us; speedup vs baseline: 2.1212x; 2.1212x over previous
//
#include <hip/hip_runtime.h>
#include <hip/hip_bf16.h>

#define THREADS 256
#define NB_MAX 400   // buckets = ceil(N/256); N=100000 -> 391
#define NPH 13       // src phases (src>>13), used only to order csr_src within a node

typedef __attribute__((ext_vector_type(8))) short bf16x8;
typedef __attribute__((ext_vector_type(4))) float f32x4;
typedef __attribute__((ext_vector_type(2))) float f32x2;

__device__ __forceinline__ unsigned short f2b(float f) {
    __hip_bfloat16 h = __float2bfloat16(f);
    return *reinterpret_cast<unsigned short*>(&h);
}
__device__ __forceinline__ unsigned char f2q(float v) {
    int q = __builtin_amdgcn_cvt_pk_fp8_f32(v, v, 0, false);
    return (unsigned char)(q & 0xff);
}
__device__ __forceinline__ void gload_lds16(const void* g, void* l) {
    __builtin_amdgcn_global_load_lds(
        (const __attribute__((address_space(1))) void*)g,
        (__attribute__((address_space(3))) void*)l, 16, 0, 0);
}

// ---------------- merged: bucket histogram (blocks < nsb) + converts (rest) ----------------
__global__ __launch_bounds__(256) void k_hist_cvt(
    const int* __restrict__ dst, int E, int nbk, int* __restrict__ gcnt, int nsb,
    const float* __restrict__ x, unsigned short* __restrict__ xb, unsigned char* __restrict__ xq,
    int N, int Npad,
    const float* __restrict__ W1l, const float* __restrict__ W1r,
    const float* __restrict__ W2l, const float* __restrict__ W2r,
    unsigned short* __restrict__ WbT, unsigned short* __restrict__ WbT2) {
    __shared__ int lc[NB_MAX];
    const int tid = threadIdx.x;
    if ((int)blockIdx.x < nsb) {
        for (int i = tid; i < nbk; i += 256) lc[i] = 0;
        __syncthreads();
        const int stride = nsb * 256;
        for (int e = blockIdx.x * 256 + tid; e < E; e += stride)
            atomicAdd(&lc[dst[e] >> 8], 1);
        __syncthreads();
        for (int i = tid; i < nbk; i += 256)
            if (lc[i]) atomicAdd(&gcnt[i], lc[i]);
        return;
    }
    int i = ((int)blockIdx.x - nsb) * 256 + tid;
    const int nxu = Npad * 32;                 // x units (8 elems each)
    if (i < nxu) {
        int row = i >> 5;
        unsigned short o[8];
        int q0 = 0, q1 = 0;
        if (row < N) {
            float4 v0 = reinterpret_cast<const float4*>(x)[2 * (size_t)i];
            float4 v1 = reinterpret_cast<const float4*>(x)[2 * (size_t)i + 1];
            o[0] = f2b(v0.x); o[1] = f2b(v0.y); o[2] = f2b(v0.z); o[3] = f2b(v0.w);
            o[4] = f2b(v1.x); o[5] = f2b(v1.y); o[6] = f2b(v1.z); o[7] = f2b(v1.w);
            q0 = __builtin_amdgcn_cvt_pk_fp8_f32(v0.x, v0.y, q0, false);
            q0 = __builtin_amdgcn_cvt_pk_fp8_f32(v0.z, v0.w, q0, true);
            q1 = __builtin_amdgcn_cvt_pk_fp8_f32(v1.x, v1.y, q1, false);
            q1 = __builtin_amdgcn_cvt_pk_fp8_f32(v1.z, v1.w, q1, true);
        } else {
            #pragma unroll
            for (int j = 0; j < 8; ++j) o[j] = 0;
        }
        reinterpret_cast<uint4*>(xb)[i] = *reinterpret_cast<uint4*>(o);
        reinterpret_cast<uint2*>(xq)[i] = make_uint2((unsigned)q0, (unsigned)q1);
        return;
    }
    int idx = i - nxu;
    if (idx < 131072) {
        int n = idx >> 9, k = idx & 511;
        float v = (k < 256) ? W1l[(size_t)k * 256 + n] : W1r[(size_t)(k - 256) * 256 + n];
        WbT[idx] = f2b(v);
    } else if (idx < 131072 + 20480) {
        int j = idx - 131072;
        int n = j >> 8, k = j & 255;
        float v = (n < 40) ? W2l[(size_t)k * 40 + n] : W2r[(size_t)k * 40 + (n - 40)];
        WbT2[j] = f2b(v);
    }
}

// ---------------- scan buckets ----------------
__global__ __launch_bounds__(512) void k_scanb(const int* __restrict__ gcnt, int* __restrict__ bptr,
                                               int* __restrict__ gcur, int nbk, int E) {
    __shared__ int sm[512];
    const int t = threadIdx.x;
    int v = (t < nbk) ? gcnt[t] : 0;
    sm[t] = v; __syncthreads();
    for (int off = 1; off < 512; off <<= 1) {
        int u = (t >= off) ? sm[t - off] : 0; __syncthreads();
        sm[t] += u; __syncthreads();
    }
    if (t < nbk) {
        int ex = sm[t] - v;
        bptr[t] = ex;
        gcur[t] = ex;
    }
    if (t == 0) bptr[nbk] = E;
}

// ---------------- scatter edges into bucket regions (packed: src<<8 | dst&255) ----------------
__global__ __launch_bounds__(256) void k_bucket_scatter(const int* __restrict__ src, const int* __restrict__ dst,
                                                        int* __restrict__ gcur, unsigned* __restrict__ pairs,
                                                        int E, int nbk) {
    __shared__ int cnt[NB_MAX];
    __shared__ int base[NB_MAX];
    const int tid = threadIdx.x;
    const int e0 = blockIdx.x * 8192;
    for (int i = tid; i < nbk; i += 256) cnt[i] = 0;
    __syncthreads();
    #pragma unroll
    for (int j = 0; j < 32; ++j) {
        int e = e0 + j * 256 + tid;
        if (e < E) atomicAdd(&cnt[dst[e] >> 8], 1);
    }
    __syncthreads();
    for (int i = tid; i < nbk; i += 256)
        base[i] = cnt[i] ? atomicAdd(&gcur[i], cnt[i]) : 0;
    __syncthreads();
    #pragma unroll
    for (int j = 0; j < 32; ++j) {
        int e = e0 + j * 256 + tid;
        if (e < E) {
            int d = dst[e];
            int p = atomicAdd(&base[d >> 8], 1);
            pairs[p] = ((unsigned)src[e] << 8) | ((unsigned)d & 255u);
        }
    }
}

// ---------------- per-bucket CSR build (per-node src-phase ordered) ----------------
__global__ __launch_bounds__(256) void k_bucket_csr(const int* __restrict__ bptr, const unsigned* __restrict__ pairs,
                                                    int* __restrict__ rowptr, float* __restrict__ dinv,
                                                    int* __restrict__ csr_src, int N, int nbk, int E) {
    __shared__ int pc[256 * NPH];   // per-(node, phase) counts -> offsets -> cursors
    __shared__ int sm[256];
    __shared__ int nodebase[256];
    const int b = blockIdx.x;
    const int tid = threadIdx.x;
    const int e0 = bptr[b], e1 = bptr[b + 1];

    #pragma unroll
    for (int i = 0; i < NPH; ++i) pc[i * 256 + tid] = 0;   // [ph][node]
    __syncthreads();
    for (int e = e0 + tid; e < e1; e += 256) {
        unsigned u = pairs[e];
        int n = (int)(u & 255u);
        int ph = (int)(u >> 8) >> 13;
        atomicAdd(&pc[ph * 256 + n], 1);
    }
    __syncthreads();
    int run = 0;
    #pragma unroll
    for (int ph = 0; ph < NPH; ++ph) {
        int c = pc[ph * 256 + tid];
        pc[ph * 256 + tid] = run;
        run += c;
    }
    int d = run;
    sm[tid] = d; __syncthreads();
    for (int off = 1; off < 256; off <<= 1) {
        int u = (tid >= off) ? sm[tid - off] : 0; __syncthreads();
        sm[tid] += u; __syncthreads();
    }
    int ex = sm[tid] - d;
    int node = (b << 8) + tid;
    int nb_ = e0 + ex;
    nodebase[tid] = nb_;
    if (node < N) {
        rowptr[node] = nb_;
        dinv[node] = 1.0f / (float)max(d, 1);
    }
    if (b == nbk - 1 && tid == 0) rowptr[N] = E;
    __syncthreads();
    #pragma unroll
    for (int ph = 0; ph < NPH; ++ph) pc[ph * 256 + tid] += nodebase[tid];
    __syncthreads();
    for (int e = e0 + tid; e < e1; e += 256) {
        unsigned u = pairs[e];
        int n = (int)(u & 255u);
        int s = (int)(u >> 8);
        int p = atomicAdd(&pc[(s >> 13) * 256 + n], 1);
        csr_src[p] = s;
    }
}

// ---------------- layer-1 gather-aggregate (fp8): half-wave per node, 8 edges in flight ----------------
__global__ __launch_bounds__(256) void k_agg1(const int* __restrict__ rowptr, const int* __restrict__ csr_src,
                                              const float* __restrict__ dinv, const unsigned char* __restrict__ xq,
                                              unsigned short* __restrict__ aggb, int N, int Npad) {
    int gid = blockIdx.x * THREADS + threadIdx.x;
    int node = gid >> 5, lane = gid & 31;
    if (node >= N) {
        if (node < Npad)
            reinterpret_cast<uint4*>(aggb + (size_t)node * 256 + lane * 8)[0] = make_uint4(0, 0, 0, 0);
        return;
    }
    const int e0 = rowptr[node], e1 = rowptr[node + 1];
    const unsigned char* xl = xq + (size_t)lane * 8;
    f32x2 acc[4];
    #pragma unroll
    for (int j = 0; j < 4; ++j) acc[j] = (f32x2){0.f, 0.f};
    for (int eb = e0; eb < e1; eb += 32) {
        int n = min(32, e1 - eb);
        int sidx = (eb + lane < e1) ? csr_src[eb + lane] : 0;
        int j = 0;
        for (; j + 7 < n; j += 8) {
            uint2 vv[8];
            #pragma unroll
            for (int q = 0; q < 8; ++q) {
                int s = __shfl(sidx, j + q, 32);
                vv[q] = *reinterpret_cast<const uint2*>(xl + (size_t)s * 256);
            }
            #pragma unroll
            for (int q = 0; q < 8; ++q) {
                acc[0] += __builtin_amdgcn_cvt_pk_f32_fp8((int)vv[q].x, false);
                acc[1] += __builtin_amdgcn_cvt_pk_f32_fp8((int)vv[q].x, true);
                acc[2] += __builtin_amdgcn_cvt_pk_f32_fp8((int)vv[q].y, false);
                acc[3] += __builtin_amdgcn_cvt_pk_f32_fp8((int)vv[q].y, true);
            }
        }
        for (; j < n; ++j) {
            int s = __shfl(sidx, j, 32);
            uint2 v = *reinterpret_cast<const uint2*>(xl + (size_t)s * 256);
            acc[0] += __builtin_amdgcn_cvt_pk_f32_fp8((int)v.x, false);
            acc[1] += __builtin_amdgcn_cvt_pk_f32_fp8((int)v.x, true);
            acc[2] += __builtin_amdgcn_cvt_pk_f32_fp8((int)v.y, false);
            acc[3] += __builtin_amdgcn_cvt_pk_f32_fp8((int)v.y, true);
        }
    }
    const float ds = dinv[node];
    unsigned short o[8];
    #pragma unroll
    for (int j = 0; j < 4; ++j) {
        o[2 * j + 0] = f2b(acc[j].x * ds);
        o[2 * j + 1] = f2b(acc[j].y * ds);
    }
    *reinterpret_cast<uint4*>(aggb + (size_t)node * 256 + lane * 8) = *reinterpret_cast<uint4*>(o);
}

// ---------------- GEMM1 (bf16 MFMA, 512 thr, 128x256 tile): h = relu([agg|x] @ [W1l;W1r] + b1) ----------------
__global__ __launch_bounds__(512) void k_gemm1(
    const unsigned short* __restrict__ aggb, const unsigned short* __restrict__ xb,
    const unsigned short* __restrict__ WbT, const float* __restrict__ b1,
    unsigned short* __restrict__ hb, int M)
{
    __shared__ unsigned short As[128 * 64];   // 128 rows (M) x 64 k
    __shared__ unsigned short Bs[256 * 64];   // 256 rows (N) x 64 k

    const int tid  = threadIdx.x;
    const int lane = tid & 63;
    const int wave = tid >> 6;                // 0..7
    const int row0 = blockIdx.x * 128;
    const int wm0  = (wave >> 2) * 64;        // 0 or 64
    const int wn0  = (wave & 3) * 64;         // 0,64,128,192

    const int ldr = lane >> 3;                       // row within 8-row chunk
    const int lsw = ((lane & 7) ^ ldr) * 8;          // swizzled global 8-elem slot

    f32x4 acc[4][4];
    #pragma unroll
    for (int m = 0; m < 4; ++m)
        #pragma unroll
        for (int n = 0; n < 4; ++n)
            acc[m][n] = (f32x4){0.f, 0.f, 0.f, 0.f};

    for (int kt = 0; kt < 8; ++kt) {
        const unsigned short* Abase = (kt < 4) ? aggb : xb;
        const int kcol = (kt & 3) * 64;
        __syncthreads();
        #pragma unroll
        for (int i = 0; i < 2; ++i) {
            const int c = wave * 2 + i;              // A chunk 0..15
            const unsigned short* ga = Abase + (size_t)(row0 + c * 8 + ldr) * 256 + kcol + lsw;
            gload_lds16(ga, &As[c * 512]);
        }
        #pragma unroll
        for (int i = 0; i < 4; ++i) {
            const int c = wave * 4 + i;              // B chunk 0..31
            const unsigned short* gb = WbT + (size_t)(c * 8 + ldr) * 512 + kt * 64 + lsw;
            gload_lds16(gb, &Bs[c * 512]);
        }
        __syncthreads();
        #pragma unroll
        for (int kk = 0; kk < 2; ++kk) {
            bf16x8 af[4], bf[4];
            #pragma unroll
            for (int m = 0; m < 4; ++m) {
                const int r = wm0 + m * 16 + (lane & 15);
                const int s = (kk * 4 + (lane >> 4)) ^ (r & 7);
                af[m] = *reinterpret_cast<const bf16x8*>(&As[r * 64 + s * 8]);
            }
            #pragma unroll
            for (int n = 0; n < 4; ++n) {
                const int r = wn0 + n * 16 + (lane & 15);
                const int s = (kk * 4 + (lane >> 4)) ^ (r & 7);
                bf[n] = *reinterpret_cast<const bf16x8*>(&Bs[r * 64 + s * 8]);
            }
            #pragma unroll
            for (int m = 0; m < 4; ++m)
                #pragma unroll
                for (int n = 0; n < 4; ++n)
                    acc[m][n] = __builtin_amdgcn_mfma_f32_16x16x32_bf16(af[m], bf[n], acc[m][n], 0, 0, 0);
        }
    }

    const int crow = (lane >> 4) * 4;
    const int ccol = lane & 15;
    #pragma unroll
    for (int n = 0; n < 4; ++n) {
        const int col = wn0 + n * 16 + ccol;
        const float bias = b1[col];
        #pragma unroll
        for (int m = 0; m < 4; ++m) {
            const int rbase = row0 + wm0 + m * 16 + crow;
            #pragma unroll
            for (int r = 0; r < 4; ++r) {
                const int row = rbase + r;
                if (row < M) {
                    float v = fmaxf(acc[m][n][r] + bias, 0.f);
                    hb[(size_t)row * 256 + col] = f2b(v);
                }
            }
        }
    }
}

// ---------------- GEMM2 (bf16 MFMA): Tq (fp8, 64B-padded rows) | Up = h @ [W2l|W2r] + b2 ----------------
__global__ __launch_bounds__(256) void k_gemm2(
    const unsigned short* __restrict__ hb, const unsigned short* __restrict__ WbT2,
    const float* __restrict__ b2,
    unsigned char* __restrict__ Tq, float* __restrict__ Up, int M)
{
    __shared__ unsigned short As[128 * 64];
    __shared__ unsigned short Bs2[80 * 264];   // padded stride 264 -> conflict-free frag reads

    const int tid  = threadIdx.x;
    const int lane = tid & 63;
    const int wave = tid >> 6;
    const int row0 = blockIdx.x * 128;

    const int ldr = lane >> 3;
    const int lsw = ((lane & 7) ^ ldr) * 8;

    // load B [80][256] into padded LDS once
    for (int idx = tid; idx < 80 * 32; idx += 256) {
        int row = idx >> 5, un = idx & 31;
        uint4 d = *reinterpret_cast<const uint4*>(WbT2 + (size_t)row * 256 + un * 8);
        *reinterpret_cast<uint4*>(&Bs2[row * 264 + un * 8]) = d;
    }

    f32x4 acc[2][5];
    #pragma unroll
    for (int m = 0; m < 2; ++m)
        #pragma unroll
        for (int n = 0; n < 5; ++n)
            acc[m][n] = (f32x4){0.f, 0.f, 0.f, 0.f};

    for (int kt = 0; kt < 4; ++kt) {
        __syncthreads();
        #pragma unroll
        for (int i = 0; i < 4; ++i) {
            const int c = wave * 4 + i;
            const unsigned short* ga = hb + (size_t)(row0 + c * 8 + ldr) * 256 + kt * 64 + lsw;
            gload_lds16(ga, &As[c * 512]);
        }
        __syncthreads();
        #pragma unroll
        for (int kk = 0; kk < 2; ++kk) {
            bf16x8 af[2], bf[5];
            #pragma unroll
            for (int m = 0; m < 2; ++m) {
                const int r = wave * 32 + m * 16 + (lane & 15);
                const int s = (kk * 4 + (lane >> 4)) ^ (r & 7);
                af[m] = *reinterpret_cast<const bf16x8*>(&As[(r & 127) * 64 + s * 8]);
            }
            #pragma unroll
            for (int n = 0; n < 5; ++n) {
                const int r = n * 16 + (lane & 15);
                bf[n] = *reinterpret_cast<const bf16x8*>(&Bs2[r * 264 + kt * 64 + kk * 32 + (lane >> 4) * 8]);
            }
            #pragma unroll
            for (int m = 0; m < 2; ++m)
                #pragma unroll
                for (int n = 0; n < 5; ++n)
                    acc[m][n] = __builtin_amdgcn_mfma_f32_16x16x32_bf16(af[m], bf[n], acc[m][n], 0, 0, 0);
        }
    }

    const int crow = (lane >> 4) * 4;
    const int ccol = lane & 15;
    #pragma unroll
    for (int n = 0; n < 5; ++n) {
        const int col = n * 16 + ccol;        // 0..79
        #pragma unroll
        for (int m = 0; m < 2; ++m) {
            const int rbase = row0 + wave * 32 + m * 16 + crow;
            #pragma unroll
            for (int r = 0; r < 4; ++r) {
                const int row = rbase + r;
                if (row < M) {
                    float v = acc[m][n][r];
                    if (col < 40)
                        Tq[(size_t)row * 64 + col] = f2q(v);
                    else
                        Up[(size_t)row * 40 + (col - 40)] = v + b2[col - 40];
                }
            }
        }
    }
    // zero the 24-byte row pad (cols 40..63) so k_final's full-row loads see zeros
    for (int i = tid; i < 128 * 24; i += 256) {
        int r = i / 24, c = 40 + (i % 24);
        int row = row0 + r;
        if (row < M) Tq[(size_t)row * 64 + c] = 0;
    }
}

// ---------------- fused layer-2 gather (fp8 Tq, 64B rows) + log_softmax: 8 edges per batch ----------------
__global__ __launch_bounds__(256) void k_final(const int* __restrict__ rowptr, const int* __restrict__ csr_src,
                                               const float* __restrict__ dinv, const unsigned char* __restrict__ Tq,
                                               const float* __restrict__ Up, float* __restrict__ out, int N) {
    int gid = blockIdx.x * THREADS + threadIdx.x;
    int node = gid >> 6, lane = gid & 63;
    if (node >= N) return;
    const int e0 = rowptr[node], e1 = rowptr[node + 1];
    const int c8 = lane & 7;     // col group: fp8 cols c8*8 .. +7
    const int e5 = lane >> 3;    // edge slot 0..7
    f32x2 acc[4];
    #pragma unroll
    for (int i = 0; i < 4; ++i) acc[i] = (f32x2){0.f, 0.f};
    for (int eb = e0; eb < e1; eb += 64) {
        int sidx = (eb + lane < e1) ? csr_src[eb + lane] : 0;
        int nn = min(64, e1 - eb);
        for (int jb = 0; jb < nn; jb += 8) {
            int ei = jb + e5;
            int s = __shfl(sidx, ei & 63, 64);
            if (ei < nn) {
                uint2 u = *reinterpret_cast<const uint2*>(Tq + (size_t)s * 64 + c8 * 8);
                acc[0] += __builtin_amdgcn_cvt_pk_f32_fp8((int)u.x, false);
                acc[1] += __builtin_amdgcn_cvt_pk_f32_fp8((int)u.x, true);
                acc[2] += __builtin_amdgcn_cvt_pk_f32_fp8((int)u.y, false);
                acc[3] += __builtin_amdgcn_cvt_pk_f32_fp8((int)u.y, true);
            }
        }
    }
    // tree-merge the 8 edge slots (lane bits 3..5), keeping col group c8
    #pragma unroll
    for (int st = 8; st <= 32; st <<= 1) {
        #pragma unroll
        for (int i = 0; i < 4; ++i) {
            acc[i].x += __shfl_xor(acc[i].x, st, 64);
            acc[i].y += __shfl_xor(acc[i].y, st, 64);
        }
    }
    // lanes 0..7 (e5==0) hold merged cols c8*8..+7; only c8<5 are real (cols<40)
    const bool act = (e5 == 0) && (c8 < 5);
    float v[8];
    float m = -1e30f;
    if (act) {
        const float ds = dinv[node];
        float4 ua = *reinterpret_cast<const float4*>(Up + (size_t)node * 40 + c8 * 8);
        float4 ub = *reinterpret_cast<const float4*>(Up + (size_t)node * 40 + c8 * 8 + 4);
        v[0] = acc[0].x * ds + ua.x; v[1] = acc[0].y * ds + ua.y;
        v[2] = acc[1].x * ds + ua.z; v[3] = acc[1].y * ds + ua.w;
        v[4] = acc[2].x * ds + ub.x; v[5] = acc[2].y * ds + ub.y;
        v[6] = acc[3].x * ds + ub.z; v[7] = acc[3].y * ds + ub.w;
        #pragma unroll
        for (int i = 0; i < 8; ++i) m = fmaxf(m, v[i]);
    }
    #pragma unroll
    for (int o = 4; o > 0; o >>= 1) m = fmaxf(m, __shfl_xor(m, o, 8));
    float e = 0.f;
    if (act) {
        #pragma unroll
        for (int i = 0; i < 8; ++i) e += expf(v[i] - m);
    }
    #pragma unroll
    for (int o = 4; o > 0; o >>= 1) e += __shfl_xor(e, o, 8);
    float ls = logf(e);
    if (act) {
        float4 oa, ob;
        oa.x = v[0] - m - ls; oa.y = v[1] - m - ls; oa.z = v[2] - m - ls; oa.w = v[3] - m - ls;
        ob.x = v[4] - m - ls; ob.y = v[5] - m - ls; ob.z = v[6] - m - ls; ob.w = v[7] - m - ls;
        *reinterpret_cast<float4*>(out + (size_t)node * 40 + c8 * 8) = oa;
        *reinterpret_cast<float4*>(out + (size_t)node * 40 + c8 * 8 + 4) = ob;
    }
}

extern "C" void kernel_launch(void* const* d_in, const int* in_sizes, int n_in,
                              void* d_out, int out_size, void* d_ws, size_t ws_size,
                              hipStream_t stream) {
    const float* x   = (const float*)d_in[0];
    const int*   ei  = (const int*)d_in[1];
    const float* W1l = (const float*)d_in[2];
    const float* W1r = (const float*)d_in[3];
    const float* b1  = (const float*)d_in[4];
    const float* W2l = (const float*)d_in[5];
    const float* W2r = (const float*)d_in[6];
    const float* b2  = (const float*)d_in[7];
    float* out = (float*)d_out;

    const int N = in_sizes[0] / 256;
    const int E = in_sizes[1] / 2;
    const int Npad = ((N + 127) / 128) * 128;
    const int nbk = (N + 255) / 256;
    const int* src = ei;
    const int* dst = ei + E;

    char* ws = (char*)d_ws;
    size_t off = 0;
    int*   gcnt    = (int*)(ws + off); off += (size_t)NB_MAX * 4;
    int*   bptr    = (int*)(ws + off); off += (size_t)(NB_MAX + 1) * 4;
    int*   gcur    = (int*)(ws + off); off += (size_t)NB_MAX * 4;
    int*   rowptr  = (int*)(ws + off); off += (size_t)(N + 1) * 4;
    float* dinv    = (float*)(ws + off); off += (size_t)N * 4;
    off = (off + 255) & ~(size_t)255;
    unsigned* pairs = (unsigned*)(ws + off); off += (size_t)E * 4;
    int*   csr_src = (int*)(ws + off); off += (size_t)E * 4;
    off = (off + 255) & ~(size_t)255;
    unsigned short* xb   = (unsigned short*)(ws + off); off += (size_t)Npad * 256 * 2;
    unsigned char*  xq   = (unsigned char*)(ws + off);  off += (size_t)Npad * 256;
    unsigned short* aggb = (unsigned short*)(ws + off); off += (size_t)Npad * 256 * 2;
    unsigned short* hb   = (unsigned short*)(ws + off); off += (size_t)Npad * 256 * 2;
    unsigned short* WbT  = (unsigned short*)(ws + off); off += (size_t)256 * 512 * 2;
    unsigned short* WbT2 = (unsigned short*)(ws + off); off += (size_t)80 * 256 * 2;
    off = (off + 255) & ~(size_t)255;
    unsigned char*  Tq   = (unsigned char*)(ws + off);  off += (size_t)Npad * 64;
    off = (off + 255) & ~(size_t)255;
    float*          Up   = (float*)(ws + off);          off += (size_t)Npad * 40 * 4;

    hipMemsetAsync(gcnt, 0, (size_t)NB_MAX * 4, stream);

    const int nsb = (E + 8191) / 8192;
    const int ncvt_blocks = (Npad * 32 + 131072 + 20480 + THREADS - 1) / THREADS;
    k_hist_cvt<<<nsb + ncvt_blocks, THREADS, 0, stream>>>(dst, E, nbk, gcnt, nsb,
                                                          x, xb, xq, N, Npad,
                                                          W1l, W1r, W2l, W2r, WbT, WbT2);
    k_scanb<<<1, 512, 0, stream>>>(gcnt, bptr, gcur, nbk, E);
    k_bucket_scatter<<<nsb, THREADS, 0, stream>>>(src, dst, gcur, pairs, E, nbk);
    k_bucket_csr<<<nbk, THREADS, 0, stream>>>(bptr, pairs, rowptr, dinv, csr_src, N, nbk, E);

    k_agg1<<<((size_t)Npad * 32 + THREADS - 1) / THREADS, THREADS, 0, stream>>>(rowptr, csr_src, dinv, xq, aggb, N, Npad);

    k_gemm1<<<Npad / 128, 512, 0, stream>>>(aggb, xb, WbT, b1, hb, N);

    k_gemm2<<<Npad / 128, THREADS, 0, stream>>>(hb, WbT2, b2, Tq, Up, N);

    k_final<<<((size_t)N * 64 + THREADS - 1) / THREADS, THREADS, 0, stream>>>(rowptr, csr_src, dinv, Tq, Up, out, N);
}